// Round 10
// baseline (495.201 us; speedup 1.0000x reference)
//
#include <hip/hip_runtime.h>

#define N_NODES 100000
#define E_EDGES 1600000
#define EP_EDGES (E_EDGES + N_NODES)   // 1,700,000 with self loops
#define SLOPE 0.2f
#define BN_EPS 1e-5f
#define NB 8                 // dst buckets (one per XCD)
#define NODES_PER_B 12500
#define NREP 32              // sub-region replicas per bucket
#define SUBREG 8192          // edges per (rep,bucket) sub-region
#define SCATTER_BLKS ((EP_EDGES + 255) / 256)

typedef _Float16 h2 __attribute__((ext_vector_type(2)));

#if defined(__has_builtin)
#if __has_builtin(__builtin_amdgcn_fdot2)
#define HAVE_FDOT2 1
#endif
#endif

__device__ __forceinline__ float fdot2f(h2 a, h2 b, float c) {
#ifdef HAVE_FDOT2
    return __builtin_amdgcn_fdot2(a, b, c, false);
#else
    return c + (float)a[0] * (float)b[0] + (float)a[1] * (float)b[1];
#endif
}
__device__ __forceinline__ h2 bch2(unsigned u) { return __builtin_bit_cast(h2, u); }
__device__ __forceinline__ h2 habs2(h2 z) {
    return __builtin_bit_cast(h2, (unsigned)(__builtin_bit_cast(unsigned, z) & 0x7fff7fffu));
}
__device__ __forceinline__ h2 shflx_h2(h2 a, int o) {
    return __builtin_bit_cast(h2, __shfl_xor(__builtin_bit_cast(int, a), o, 64));
}

// DPP rotate-reduce: sum across each 16-lane row, pure VALU
template <int CTRL>
__device__ __forceinline__ float dpp_add_step(float v) {
    int r = __builtin_amdgcn_update_dpp(0, __float_as_int(v), CTRL, 0xF, 0xF, false);
    return v + __int_as_float(r);
}
__device__ __forceinline__ float rowsum16(float v) {
    v = dpp_add_step<0x128>(v);
    v = dpp_add_step<0x124>(v);
    v = dpp_add_step<0x122>(v);
    v = dpp_add_step<0x121>(v);
    return v;
}

// ---------- bucket_scatter body (u32-packed edges: (dlocal<<17)|src) ----------
__device__ __forceinline__ void bucket_scatter_body(int bid, const int* __restrict__ src,
                                                    const int* __restrict__ dst,
                                                    int* __restrict__ gcur, unsigned* __restrict__ ebuf) {
    int i = bid * 256 + threadIdx.x;
    int rep = bid & (NREP - 1);
    bool active = i < EP_EDGES;
    int s = 0, d = 0;
    if (i < E_EDGES) { s = src[i]; d = dst[i]; }
    else if (active) { s = i - E_EDGES; d = s; }
    int b = active ? (int)((unsigned)d / NODES_PER_B) : NB;
    unsigned long long lt = (1ull << (threadIdx.x & 63)) - 1ull;
    int rank = 0;
    unsigned long long mymask = 0;
#pragma unroll
    for (int bb = 0; bb < NB; ++bb) {
        unsigned long long m = __ballot(b == bb);
        if (b == bb) { rank = __popcll(m & lt); mymask = m; }
    }
    int leader = mymask ? (__ffsll((long long)mymask) - 1) : 0;
    int lanebit = threadIdx.x & 63;
    int chunkbase = 0;
    if (active && lanebit == leader)
        chunkbase = atomicAdd(&gcur[rep * NB + b], (int)__popcll(mymask));
    chunkbase = __shfl(chunkbase, leader, 64);
    if (active) {
        unsigned dl = (unsigned)d - (unsigned)b * NODES_PER_B;
        ebuf[(size_t)(rep * NB + b) * SUBREG + chunkbase + rank] = (dl << 17) | (unsigned)s;
    }
}

// ---------- fuse_enc body: fold encoder into layer-0 weights ----------
__device__ __forceinline__ void fuse_enc_body(const float* __restrict__ We, const float* __restrict__ be,
                                              const float* __restrict__ Wl, const float* __restrict__ bl,
                                              const float* __restrict__ Wr, const float* __restrict__ br,
                                              float* __restrict__ Wcl, float* __restrict__ bcl,
                                              float* __restrict__ Wcr, float* __restrict__ bcr,
                                              float (*sWe)[64], float* sbe) {
    int t = threadIdx.x;
    for (int i = t; i < 4096; i += 256) sWe[i & 63][i >> 6] = We[i];
    if (t < 64) sbe[t] = be[t];
    __syncthreads();
    int j = t & 127, side = t >> 7;
    const float* W  = side ? Wr : Wl;
    const float* bb = side ? br : bl;
    float acc[64];
#pragma unroll
    for (int k = 0; k < 64; ++k) acc[k] = 0.f;
    float bacc = bb[j];
    for (int m = 0; m < 64; ++m) {
        float wv = W[m * 128 + j];
        bacc += sbe[m] * wv;
#pragma unroll
        for (int k = 0; k < 64; ++k) acc[k] += sWe[m][k] * wv;
    }
    float* Wc = side ? Wcr : Wcl;
#pragma unroll
    for (int k = 0; k < 64; ++k) Wc[k * 128 + j] = acc[k];
    (side ? bcr : bcl)[j] = bacc;
}

// ---------- combined: block 0 = fuse_enc, blocks 1.. = bucket_scatter ----------
__global__ __launch_bounds__(256) void scatter_fuse(const int* __restrict__ src, const int* __restrict__ dst,
                                                    int* __restrict__ gcur, unsigned* __restrict__ ebuf,
                                                    const float* __restrict__ We, const float* __restrict__ be,
                                                    const float* __restrict__ Wl, const float* __restrict__ bl,
                                                    const float* __restrict__ Wr, const float* __restrict__ br,
                                                    float* __restrict__ Wcl, float* __restrict__ bcl,
                                                    float* __restrict__ Wcr, float* __restrict__ bcr) {
    __shared__ float sWe[64][64];
    __shared__ float sbe[64];
    if (blockIdx.x == 0)
        fuse_enc_body(We, be, Wl, bl, Wr, br, Wcl, bcl, Wcr, bcr, sWe, sbe);
    else
        bucket_scatter_body(blockIdx.x - 1, src, dst, gcur, ebuf);
}

// ---------- per-layer transforms body, f16 chunks; 2 columns/thread, 16-row tiles ----------
// node chunk k (16B): [h0 c4k..4k+3 | h1 c4k..4k+3], element idx = (c>>2)*8 + head*4 + (c&3)
template <int BN>
__device__ __forceinline__ void layer_gemm_body(int bid, int nb,
                                                const float* __restrict__ hin,
                                                const float* __restrict__ Wl, const float* __restrict__ bl,
                                                const float* __restrict__ Wr, const float* __restrict__ br,
                                                const float* __restrict__ bns, const float* __restrict__ gamma,
                                                const float* __restrict__ beta,
                                                unsigned short* __restrict__ xl, unsigned short* __restrict__ xr,
                                                float* ssc, float* ssh, h2 (*sh)[36]) {
    int t = threadIdx.x;
    if (BN) {
        if (t < 64) {
            float s = 0.f, sq = 0.f;
#pragma unroll
            for (int r = 0; r < 8; ++r) { s += bns[r * 128 + t]; sq += bns[r * 128 + 64 + t]; }
            float mu = s * (1.f / N_NODES);
            float var = sq * (1.f / N_NODES) - mu * mu;
            float sc = gamma[t] * rsqrtf(var + BN_EPS);
            ssc[t] = sc; ssh[t] = beta[t] - mu * sc;
        }
        __syncthreads();
    }
    int p = t & 127, rh = t >> 7;          // column pair, row half
    int col0 = 2 * p;                       // even: col0,col0+1 same side
    bool isR = col0 >= 128;
    int cw0 = col0 & 127, cw1 = cw0 + 1;
    const float* W = isR ? Wr : Wl;
    h2 w2a[32], w2b[32];
#pragma unroll
    for (int k2 = 0; k2 < 32; ++k2) {
        w2a[k2] = (h2){(_Float16)W[(2 * k2) * 128 + cw0], (_Float16)W[(2 * k2 + 1) * 128 + cw0]};
        w2b[k2] = (h2){(_Float16)W[(2 * k2) * 128 + cw1], (_Float16)W[(2 * k2 + 1) * 128 + cw1]};
    }
    float bja = (isR ? br : bl)[cw0];
    float bjb = (isR ? br : bl)[cw1];
    int head0 = cw0 >> 6, c0 = cw0 & 63;
    int head1 = cw1 >> 6, c1 = cw1 & 63;
    int oidx0 = ((c0 >> 2) << 3) + (head0 << 2) + (c0 & 3);
    int oidx1 = ((c1 >> 2) << 3) + (head1 << 2) + (c1 & 3);
    unsigned short* dstp = isR ? xr : xl;
    for (int base = bid * 16; base < N_NODES; base += nb * 16) {
        __syncthreads();
#pragma unroll
        for (int pass = 0; pass < 2; ++pass) {
            int i = t + pass * 256;
            int node = i >> 5, pr = i & 31;
            int gnode = base + node;
            int cc = pr * 2;
            float2 v = make_float2(0.f, 0.f);
            if (gnode < N_NODES) v = *(const float2*)(hin + (size_t)gnode * 64 + cc);
            if (BN) {
                v.x = fmaxf(v.x * ssc[cc] + ssh[cc], 0.f);
                v.y = fmaxf(v.y * ssc[cc + 1] + ssh[cc + 1], 0.f);
            }
            sh[node][pr] = (h2){(_Float16)v.x, (_Float16)v.y};
        }
        __syncthreads();
        int lim = min(16, N_NODES - base);
        int rend = min(rh * 8 + 8, lim);
        for (int r = rh * 8; r < rend; ++r) {
            float acca = bja, accb = bjb;
            const uint4* r4 = (const uint4*)(&sh[r][0]);
#pragma unroll
            for (int k4 = 0; k4 < 8; ++k4) {
                uint4 u = r4[k4];
                acca = fdot2f(bch2(u.x), w2a[4 * k4 + 0], acca);
                accb = fdot2f(bch2(u.x), w2b[4 * k4 + 0], accb);
                acca = fdot2f(bch2(u.y), w2a[4 * k4 + 1], acca);
                accb = fdot2f(bch2(u.y), w2b[4 * k4 + 1], accb);
                acca = fdot2f(bch2(u.z), w2a[4 * k4 + 2], acca);
                accb = fdot2f(bch2(u.z), w2b[4 * k4 + 2], accb);
                acca = fdot2f(bch2(u.w), w2a[4 * k4 + 3], acca);
                accb = fdot2f(bch2(u.w), w2b[4 * k4 + 3], accb);
            }
            size_t rowb = (size_t)(base + r) * 128;
            dstp[rowb + oidx0] = __builtin_bit_cast(unsigned short, (_Float16)acca);
            dstp[rowb + oidx1] = __builtin_bit_cast(unsigned short, (_Float16)accb);
        }
    }
}

// ---------- combined: blocks 0..255 = bucket_deg (u16-packed LDS histo), 256.. = layer_gemm<0> ----------
__global__ __launch_bounds__(256) void deg_gemm0(const int* __restrict__ gcur,
                                                 const unsigned* __restrict__ ebuf,
                                                 int* __restrict__ deg,
                                                 const float* __restrict__ hin,
                                                 const float* __restrict__ Wl, const float* __restrict__ bl,
                                                 const float* __restrict__ Wr, const float* __restrict__ br,
                                                 unsigned short* __restrict__ xl, unsigned short* __restrict__ xr) {
    __shared__ unsigned ldeg2[NODES_PER_B / 2];   // 25 KB: two u16 counts per u32
    __shared__ float ssc[64], ssh[64];
    __shared__ h2 sh[16][36];
    if (blockIdx.x < NREP * NB) {
        int b = blockIdx.x & (NB - 1), rep = blockIdx.x >> 3;
        for (int j = threadIdx.x; j < NODES_PER_B / 2; j += 256) ldeg2[j] = 0;
        __syncthreads();
        int cnt = gcur[rep * NB + b];
        int base = b * NODES_PER_B;
        const unsigned* p = ebuf + (size_t)(rep * NB + b) * SUBREG;
        for (int i = threadIdx.x; i < cnt; i += 256) {
            unsigned dl = p[i] >> 17;
            atomicAdd(&ldeg2[dl >> 1], 1u << ((dl & 1) * 16));
        }
        __syncthreads();
        for (int j = threadIdx.x; j < NODES_PER_B; j += 256) {
            unsigned v = (ldeg2[j >> 1] >> ((j & 1) * 16)) & 0xffffu;
            if (v) atomicAdd(&deg[base + j], (int)v);
        }
    } else {
        layer_gemm_body<0>(blockIdx.x - NREP * NB, 1024, hin, Wl, bl, Wr, br,
                           nullptr, nullptr, nullptr, xl, xr, ssc, ssh, sh);
    }
}

// ---------- bucket_fine (standalone: col scatter needs quiet L2) ----------
__global__ __launch_bounds__(256) void bucket_fine(const int* __restrict__ gcur,
                                                   const unsigned* __restrict__ ebuf,
                                                   int* __restrict__ cursor, int* __restrict__ col) {
    int b = blockIdx.x & (NB - 1), rep = blockIdx.x >> 3;
    int cnt = gcur[rep * NB + b];
    int base = b * NODES_PER_B;
    const unsigned* p = ebuf + (size_t)(rep * NB + b) * SUBREG;
    for (int i = threadIdx.x; i < cnt; i += 256) {
        unsigned e = p[i];
        int d = base + (int)(e >> 17), s = (int)(e & 0x1FFFFu);
        int pos = atomicAdd(&cursor[d], 1);
        col[pos] = s;
    }
}

// ---------- scans for row_ptr (wave-scan) ----------
__global__ void scan_a(const int* __restrict__ deg, int* __restrict__ row_ptr, int* __restrict__ bsum) {
    __shared__ int wsum[16];
    int tid = threadIdx.x;
    int lane = tid & 63;
    int i = blockIdx.x * 1024 + tid;
    int x = (i < N_NODES) ? deg[i] : 0;
#pragma unroll
    for (int o = 1; o < 64; o <<= 1) {
        int y = __shfl_up(x, o, 64);
        if (lane >= o) x += y;
    }
    if (lane == 63) wsum[tid >> 6] = x;
    __syncthreads();
    if (tid < 16) {
        int s = wsum[tid];
#pragma unroll
        for (int o = 1; o < 16; o <<= 1) {
            int y = __shfl_up(s, o, 16);
            if (tid >= o) s += y;
        }
        wsum[tid] = s;
    }
    __syncthreads();
    int pre = (tid >= 64) ? wsum[(tid >> 6) - 1] : 0;
    int incl = x + pre;
    if (i < N_NODES) row_ptr[i + 1] = incl;
    if (tid == 1023) bsum[blockIdx.x] = incl;
}

// scan_c with inline block-sum prefix
__global__ void scan_c(int* __restrict__ cursor, int* __restrict__ row_ptr, const int* __restrict__ bsum) {
    __shared__ int sp[128];
    int t = threadIdx.x;
    if (t < 128) sp[t] = (t < 98) ? bsum[t] : 0;
    __syncthreads();
    for (int o = 1; o < 128; o <<= 1) {
        int v = (t < 128 && t >= o) ? sp[t - o] : 0;
        __syncthreads();
        if (t < 128) sp[t] += v;
        __syncthreads();
    }
    int i = blockIdx.x * 256 + t;
    if (i < N_NODES) {
        int d = cursor[i];
        int blk = i >> 10;
        int pre = blk ? sp[blk - 1] : 0;
        int incl = row_ptr[i + 1] + pre;
        row_ptr[i + 1] = incl;
        cursor[i] = incl - d;           // exclusive start
        if (i == 0) row_ptr[0] = 0;
    }
}

// ---------- standalone layer 1 transform (BN fused) ----------
__global__ __launch_bounds__(256) void layer_gemm1(const float* __restrict__ hin,
                                                   const float* __restrict__ Wl, const float* __restrict__ bl,
                                                   const float* __restrict__ Wr, const float* __restrict__ br,
                                                   const float* __restrict__ bns, const float* __restrict__ gamma,
                                                   const float* __restrict__ beta,
                                                   unsigned short* __restrict__ xl, unsigned short* __restrict__ xr) {
    __shared__ float ssc[64], ssh[64];
    __shared__ h2 sh[16][36];
    layer_gemm_body<1>(blockIdx.x, gridDim.x, hin, Wl, bl, Wr, br, bns, gamma, beta, xl, xr, ssc, ssh, sh);
}

// ---------- fused GATv2 edge phase: 2 dst nodes per wave (dual-stream), packed-f16 ----------
__global__ __launch_bounds__(256) void aggregate(const char* __restrict__ xlb,
                                                 const uint4* __restrict__ xr4,
                                                 const int* __restrict__ row_ptr, const int* __restrict__ col,
                                                 const float* __restrict__ att_l, const float* __restrict__ bias_l,
                                                 float* __restrict__ hn, float* __restrict__ bnsum) {
    int lane = threadIdx.x & 63, wid = threadIdx.x >> 6;
    int q = lane >> 4, k = lane & 15;
    int koff = k << 4;
    h2 atA0 = {(_Float16)att_l[4 * k], (_Float16)att_l[4 * k + 1]};
    h2 atA1 = {(_Float16)att_l[4 * k + 2], (_Float16)att_l[4 * k + 3]};
    h2 atB0 = {(_Float16)att_l[64 + 4 * k], (_Float16)att_l[64 + 4 * k + 1]};
    h2 atB1 = {(_Float16)att_l[64 + 4 * k + 2], (_Float16)att_l[64 + 4 * k + 3]};
    float bi0 = bias_l[4 * k], bi1 = bias_l[4 * k + 1], bi2 = bias_l[4 * k + 2], bi3 = bias_l[4 * k + 3];
    const h2 c06 = {(_Float16)0.6f, (_Float16)0.6f};
    const h2 c04 = {(_Float16)0.4f, (_Float16)0.4f};
    float ps[4] = {0, 0, 0, 0}, pq[4] = {0, 0, 0, 0};
    int w = blockIdx.x * 4 + wid, nw = gridDim.x * 4;
    for (int vb = w; vb < N_NODES; vb += 2 * nw) {
        bool has1 = (vb + nw) < N_NODES;
        int va[2]; va[0] = vb; va[1] = has1 ? vb + nw : vb;
        h2 rA0[2], rA1[2], rB0[2], rB1[2];
        int len[2];
        const int* cptr[2];
        int cv2[2], cv3[2];
        uint4 lp0[2], lp1[2];
        float s0[2] = {0.f, 0.f}, s1[2] = {0.f, 0.f};
        h2 aA0[2] = {{0, 0}, {0, 0}}, aA1[2] = {{0, 0}, {0, 0}};
        h2 aB0[2] = {{0, 0}, {0, 0}}, aB1[2] = {{0, 0}, {0, 0}};
#pragma unroll
        for (int u = 0; u < 2; ++u) {
            uint4 rp = xr4[(size_t)va[u] * 16 + k];
            rA0[u] = bch2(rp.x); rA1[u] = bch2(rp.y); rB0[u] = bch2(rp.z); rB1[u] = bch2(rp.w);
            int b = row_ptr[va[u]], e = row_ptr[va[u] + 1];
            int l = (u == 1 && !has1) ? 0 : (e - b);
            len[u] = l;
            cptr[u] = col + b + q;            // padded col: over-read safe
            int c0 = cptr[u][0], c1 = cptr[u][4];
            cv2[u] = cptr[u][8]; cv3[u] = cptr[u][12];
            cptr[u] += 16;
            lp0[u] = *(const uint4*)(xlb + (((size_t)(unsigned)c0) << 8) + koff);
            lp1[u] = lp0[u];
            if (4 < l) lp1[u] = *(const uint4*)(xlb + (((size_t)(unsigned)c1) << 8) + koff);
        }
        int n = max(len[0], len[1]);
        for (int j = 0; j < n; j += 4) {
#pragma unroll
            for (int u = 0; u < 2; ++u) {
                uint4 lp2 = lp1[u];
                if (j + 8 < len[u])
                    lp2 = *(const uint4*)(xlb + (((size_t)(unsigned)cv2[u]) << 8) + koff);
                cv2[u] = cv3[u];
                cv3[u] = *cptr[u]; cptr[u] += 4;
                h2 lA0 = bch2(lp0[u].x), lA1 = bch2(lp0[u].y), lB0 = bch2(lp0[u].z), lB1 = bch2(lp0[u].w);
                h2 zA0 = lA0 + rA0[u], zA1 = lA1 + rA1[u], zB0 = lB0 + rB0[u], zB1 = lB1 + rB1[u];
                h2 yA0 = zA0 * c06 + habs2(zA0) * c04;
                h2 yA1 = zA1 * c06 + habs2(zA1) * c04;
                h2 yB0 = zB0 * c06 + habs2(zB0) * c04;
                h2 yB1 = zB1 * c06 + habs2(zB1) * c04;
                float t0 = fdot2f(yA1, atA1, fdot2f(yA0, atA0, 0.f));
                float t1 = fdot2f(yB1, atB1, fdot2f(yB0, atB0, 0.f));
                t0 = rowsum16(t0); t1 = rowsum16(t1);
                bool valid = (j + q) < len[u];
                float p0 = valid ? __expf(t0) : 0.f;
                float p1 = valid ? __expf(t1) : 0.f;
                s0[u] += p0; s1[u] += p1;
                h2 p0h = {(_Float16)p0, (_Float16)p0};
                h2 p1h = {(_Float16)p1, (_Float16)p1};
                aA0[u] += p0h * lA0; aA1[u] += p0h * lA1;
                aB0[u] += p1h * lB0; aB1[u] += p1h * lB1;
                lp0[u] = lp1[u]; lp1[u] = lp2;
            }
        }
#pragma unroll
        for (int u = 0; u < 2; ++u) {
            if (u == 0 || has1) {
                float S0 = s0[u], S1 = s1[u];
                h2 A0 = aA0[u], A1 = aA1[u], B0 = aB0[u], B1 = aB1[u];
#pragma unroll
                for (int o = 16; o <= 32; o <<= 1) {
                    S0 += __shfl_xor(S0, o, 64); S1 += __shfl_xor(S1, o, 64);
                    A0 += shflx_h2(A0, o); A1 += shflx_h2(A1, o);
                    B0 += shflx_h2(B0, o); B1 += shflx_h2(B1, o);
                }
                if (q == 0) {
                    float i0 = 0.5f / S0, i1 = 0.5f / S1;
                    float hv0 = (float)A0[0] * i0 + (float)B0[0] * i1 + bi0;
                    float hv1 = (float)A0[1] * i0 + (float)B0[1] * i1 + bi1;
                    float hv2 = (float)A1[0] * i0 + (float)B1[0] * i1 + bi2;
                    float hv3 = (float)A1[1] * i0 + (float)B1[1] * i1 + bi3;
                    *(float4*)(hn + (size_t)va[u] * 64 + 4 * k) = make_float4(hv0, hv1, hv2, hv3);
                    ps[0] += hv0; pq[0] += hv0 * hv0;
                    ps[1] += hv1; pq[1] += hv1 * hv1;
                    ps[2] += hv2; pq[2] += hv2 * hv2;
                    ps[3] += hv3; pq[3] += hv3 * hv3;
                }
            }
        }
    }
    __shared__ float sb[2][4][64];
    if (q == 0) {
#pragma unroll
        for (int j = 0; j < 4; ++j) { sb[0][wid][4 * k + j] = ps[j]; sb[1][wid][4 * k + j] = pq[j]; }
    }
    __syncthreads();
    float* dstb = bnsum + (size_t)(blockIdx.x & 7) * 128;
    int t = threadIdx.x;
    if (t < 64)
        atomicAdd(&dstb[t], sb[0][0][t] + sb[0][1][t] + sb[0][2][t] + sb[0][3][t]);
    else if (t < 128)
        atomicAdd(&dstb[t], sb[1][0][t - 64] + sb[1][1][t - 64] + sb[1][2][t - 64] + sb[1][3][t - 64]);
}

// ---------- pool: batch sorted -> per-graph blocks via binary search; BN fused ----------
__global__ __launch_bounds__(256) void pool2(const float* __restrict__ hn, const int* __restrict__ batch,
                                             const float* __restrict__ bns, const float* __restrict__ gamma,
                                             const float* __restrict__ beta,
                                             float* __restrict__ gpool, float* __restrict__ gcnt) {
    __shared__ float ssc[64], ssh[64];
    int t = threadIdx.x;
    if (t < 64) {
        float s = 0.f, sq = 0.f;
#pragma unroll
        for (int r = 0; r < 8; ++r) { s += bns[r * 128 + t]; sq += bns[r * 128 + 64 + t]; }
        float mu = s * (1.f / N_NODES);
        float var = sq * (1.f / N_NODES) - mu * mu;
        float sc = gamma[t] * rsqrtf(var + BN_EPS);
        ssc[t] = sc; ssh[t] = beta[t] - mu * sc;
    }
    __syncthreads();
    int g = blockIdx.x >> 2, part = blockIdx.x & 3;
    int lo = 0, hi = N_NODES;
    while (lo < hi) { int mid = (lo + hi) >> 1; if (batch[mid] < g) lo = mid + 1; else hi = mid; }
    int lo2 = lo, hi2 = N_NODES;
    while (lo2 < hi2) { int mid = (lo2 + hi2) >> 1; if (batch[mid] < g + 1) lo2 = mid + 1; else hi2 = mid; }
    int len = lo2 - lo;
    if (part == 0 && t == 0) gcnt[g] = (float)len;
    int n0 = lo + (len * part) / 4, n1 = lo + (len * (part + 1)) / 4;
    int c = t & 63, r = t >> 6;
    float sc = ssc[c], sh = ssh[c];
    float acc = 0.f;
    for (int node = n0 + r; node < n1; node += 4)
        acc += fmaxf(hn[(size_t)node * 64 + c] * sc + sh, 0.f);
    __shared__ float sb[4][64];
    sb[r][c] = acc;
    __syncthreads();
    if (r == 0)
        atomicAdd(&gpool[g * 64 + c], sb[0][c] + sb[1][c] + sb[2][c] + sb[3][c]);
}

// ---------- classifier ----------
__global__ void classify(const float* __restrict__ gpool, const float* __restrict__ gcnt,
                         const float* __restrict__ Wc, const float* __restrict__ bc, float* __restrict__ out) {
    int t = threadIdx.x;
    if (t >= 640) return;
    int b = t / 10, o = t % 10;
    float inv = 1.f / fmaxf(gcnt[b], 1.f);
    float acc = 0.f;
    for (int c = 0; c < 64; ++c) acc += gpool[b * 64 + c] * Wc[c * 10 + o];
    out[t] = acc * inv + bc[o];
}

extern "C" void kernel_launch(void* const* d_in, const int* in_sizes, int n_in,
                              void* d_out, int out_size, void* d_ws, size_t ws_size,
                              hipStream_t stream) {
    (void)in_sizes; (void)n_in; (void)out_size; (void)ws_size;
    const float* x     = (const float*)d_in[0];
    const int*   ei    = (const int*)d_in[1];
    const int*   batch = (const int*)d_in[2];
    const float* W_enc = (const float*)d_in[3];
    const float* b_enc = (const float*)d_in[4];
    const float* Wl    = (const float*)d_in[5];
    const float* bl    = (const float*)d_in[6];
    const float* Wr    = (const float*)d_in[7];
    const float* br    = (const float*)d_in[8];
    const float* att   = (const float*)d_in[9];
    const float* bias  = (const float*)d_in[10];
    const float* gamma = (const float*)d_in[11];
    const float* beta  = (const float*)d_in[12];
    const float* Wc    = (const float*)d_in[13];
    const float* bc    = (const float*)d_in[14];
    float* out = (float*)d_out;

    char* ws = (char*)d_ws;
    size_t off = 0;
    auto A = [&](size_t bytes) { size_t r = off; off += (bytes + 255) & ~(size_t)255; return r; };

    int* row_ptr = (int*)(ws + A((N_NODES + 1) * 4));
    // colv followed immediately by the contiguous zero region (one memset)
    size_t colv_off = A((size_t)EP_EDGES * 4 + 426240);
    int* colv = (int*)(ws + colv_off);
    char* zbase = ws + colv_off + (size_t)EP_EDGES * 4;
    int*   cursor = (int*)(zbase + 128);              // 400000 B  (col pad = zbase+0, 128 B)
    int*   gcur   = (int*)(zbase + 400128);           // 1024 B
    float* bns    = (float*)(zbase + 401152);         // 8192 B (2 layers x 8 reps x 128)
    float* gpool  = (float*)(zbase + 409344);         // 16384 B
    float* gcnt   = (float*)(zbase + 425728);         // 256 B
    const size_t ZBYTES = 426240;

    float* h   = (float*)(ws + A((size_t)N_NODES * 64 * 4));
    float* hn  = (float*)(ws + A((size_t)N_NODES * 64 * 4));
    unsigned short* xl = (unsigned short*)(ws + A((size_t)N_NODES * 128 * 2));
    unsigned short* xr = (unsigned short*)(ws + A((size_t)N_NODES * 128 * 2));
    unsigned* ebuf = (unsigned*)(ws + A((size_t)NREP * NB * SUBREG * 4));
    int* bsum  = (int*)(ws + A(512));
    float* Wcl = (float*)(ws + A(64 * 128 * 4));
    float* Wcr = (float*)(ws + A(64 * 128 * 4));
    float* bcl = (float*)(ws + A(128 * 4));
    float* bcr = (float*)(ws + A(128 * 4));

    const int* srcv = ei;
    const int* dstv = ei + E_EDGES;

    hipMemsetAsync(zbase, 0, ZBYTES, stream);

    // bucket_scatter ∥ fuse_enc
    scatter_fuse<<<SCATTER_BLKS + 1, 256, 0, stream>>>(srcv, dstv, gcur, ebuf,
                                                       W_enc, b_enc, Wl, bl, Wr, br,
                                                       Wcl, bcl, Wcr, bcr);
    // bucket_deg ∥ layer_gemm<0> (deg is LDS-only: no L2 thrash against gemm writes)
    deg_gemm0<<<NREP * NB + 1024, 256, 0, stream>>>(gcur, ebuf, cursor,
                                                    x, Wcl, bcl, Wcr, bcr, xl, xr);
    scan_a<<<98, 1024, 0, stream>>>(cursor, row_ptr, bsum);
    scan_c<<<(N_NODES + 255) / 256, 256, 0, stream>>>(cursor, row_ptr, bsum);
    bucket_fine<<<NREP * NB, 256, 0, stream>>>(gcur, ebuf, cursor, colv);

    aggregate<<<4096, 256, 0, stream>>>((const char*)xl, (const uint4*)xr,
                                        row_ptr, colv, att, bias, hn, bns);
    // layer 1 (BN of layer 0 folded into prologue)
    layer_gemm1<<<1024, 256, 0, stream>>>(hn, Wl + 64 * 128, bl + 128, Wr + 64 * 128, br + 128,
                                          bns, gamma, beta, xl, xr);
    aggregate<<<4096, 256, 0, stream>>>((const char*)xl, (const uint4*)xr,
                                        row_ptr, colv, att + 128, bias + 64, h, bns + 1024);

    // pool (BN of layer 1 fused) + classifier
    pool2<<<256, 256, 0, stream>>>(h, batch, bns + 1024, gamma + 64, beta + 64, gpool, gcnt);
    classify<<<1, 640, 0, stream>>>(gpool, gcnt, Wc, bc, out);
}

// Round 11
// 432.525 us; speedup vs baseline: 1.1449x; 1.1449x over previous
//
#include <hip/hip_runtime.h>

#define N_NODES 100000
#define E_EDGES 1600000
#define EP_EDGES (E_EDGES + N_NODES)   // 1,700,000 with self loops
#define SLOPE 0.2f
#define BN_EPS 1e-5f
#define NB 8                 // dst buckets (one per XCD)
#define NODES_PER_B 12500
#define NREP 32              // sub-region replicas per bucket
#define SUBREG 8192          // edges per (rep,bucket) sub-region
#define SCATTER_BLKS ((EP_EDGES + 255) / 256)

typedef _Float16 h2 __attribute__((ext_vector_type(2)));

#if defined(__has_builtin)
#if __has_builtin(__builtin_amdgcn_fdot2)
#define HAVE_FDOT2 1
#endif
#endif

__device__ __forceinline__ float fdot2f(h2 a, h2 b, float c) {
#ifdef HAVE_FDOT2
    return __builtin_amdgcn_fdot2(a, b, c, false);
#else
    return c + (float)a[0] * (float)b[0] + (float)a[1] * (float)b[1];
#endif
}
__device__ __forceinline__ h2 bch2(unsigned u) { return __builtin_bit_cast(h2, u); }
__device__ __forceinline__ h2 habs2(h2 z) {
    return __builtin_bit_cast(h2, (unsigned)(__builtin_bit_cast(unsigned, z) & 0x7fff7fffu));
}
__device__ __forceinline__ h2 shflx_h2(h2 a, int o) {
    return __builtin_bit_cast(h2, __shfl_xor(__builtin_bit_cast(int, a), o, 64));
}

// DPP rotate-reduce: sum across each 16-lane row, pure VALU
template <int CTRL>
__device__ __forceinline__ float dpp_add_step(float v) {
    int r = __builtin_amdgcn_update_dpp(0, __float_as_int(v), CTRL, 0xF, 0xF, false);
    return v + __int_as_float(r);
}
__device__ __forceinline__ float rowsum16(float v) {
    v = dpp_add_step<0x128>(v);
    v = dpp_add_step<0x124>(v);
    v = dpp_add_step<0x122>(v);
    v = dpp_add_step<0x121>(v);
    return v;
}

// ---------- bucket_scatter body (u32-packed edges: (dlocal<<17)|src) ----------
__device__ __forceinline__ void bucket_scatter_body(int bid, const int* __restrict__ src,
                                                    const int* __restrict__ dst,
                                                    int* __restrict__ gcur, unsigned* __restrict__ ebuf) {
    int i = bid * 256 + threadIdx.x;
    int rep = bid & (NREP - 1);
    bool active = i < EP_EDGES;
    int s = 0, d = 0;
    if (i < E_EDGES) { s = src[i]; d = dst[i]; }
    else if (active) { s = i - E_EDGES; d = s; }
    int b = active ? (int)((unsigned)d / NODES_PER_B) : NB;
    unsigned long long lt = (1ull << (threadIdx.x & 63)) - 1ull;
    int rank = 0;
    unsigned long long mymask = 0;
#pragma unroll
    for (int bb = 0; bb < NB; ++bb) {
        unsigned long long m = __ballot(b == bb);
        if (b == bb) { rank = __popcll(m & lt); mymask = m; }
    }
    int leader = mymask ? (__ffsll((long long)mymask) - 1) : 0;
    int lanebit = threadIdx.x & 63;
    int chunkbase = 0;
    if (active && lanebit == leader)
        chunkbase = atomicAdd(&gcur[rep * NB + b], (int)__popcll(mymask));
    chunkbase = __shfl(chunkbase, leader, 64);
    if (active) {
        unsigned dl = (unsigned)d - (unsigned)b * NODES_PER_B;
        ebuf[(size_t)(rep * NB + b) * SUBREG + chunkbase + rank] = (dl << 17) | (unsigned)s;
    }
}

// ---------- fuse_enc body: fold encoder into layer-0 weights ----------
__device__ __forceinline__ void fuse_enc_body(const float* __restrict__ We, const float* __restrict__ be,
                                              const float* __restrict__ Wl, const float* __restrict__ bl,
                                              const float* __restrict__ Wr, const float* __restrict__ br,
                                              float* __restrict__ Wcl, float* __restrict__ bcl,
                                              float* __restrict__ Wcr, float* __restrict__ bcr,
                                              float (*sWe)[64], float* sbe) {
    int t = threadIdx.x;
    for (int i = t; i < 4096; i += 256) sWe[i & 63][i >> 6] = We[i];
    if (t < 64) sbe[t] = be[t];
    __syncthreads();
    int j = t & 127, side = t >> 7;
    const float* W  = side ? Wr : Wl;
    const float* bb = side ? br : bl;
    float acc[64];
#pragma unroll
    for (int k = 0; k < 64; ++k) acc[k] = 0.f;
    float bacc = bb[j];
    for (int m = 0; m < 64; ++m) {
        float wv = W[m * 128 + j];
        bacc += sbe[m] * wv;
#pragma unroll
        for (int k = 0; k < 64; ++k) acc[k] += sWe[m][k] * wv;
    }
    float* Wc = side ? Wcr : Wcl;
#pragma unroll
    for (int k = 0; k < 64; ++k) Wc[k * 128 + j] = acc[k];
    (side ? bcr : bcl)[j] = bacc;
}

// ---------- combined: block 0 = fuse_enc, blocks 1.. = bucket_scatter ----------
__global__ __launch_bounds__(256) void scatter_fuse(const int* __restrict__ src, const int* __restrict__ dst,
                                                    int* __restrict__ gcur, unsigned* __restrict__ ebuf,
                                                    const float* __restrict__ We, const float* __restrict__ be,
                                                    const float* __restrict__ Wl, const float* __restrict__ bl,
                                                    const float* __restrict__ Wr, const float* __restrict__ br,
                                                    float* __restrict__ Wcl, float* __restrict__ bcl,
                                                    float* __restrict__ Wcr, float* __restrict__ bcr) {
    __shared__ float sWe[64][64];
    __shared__ float sbe[64];
    if (blockIdx.x == 0)
        fuse_enc_body(We, be, Wl, bl, Wr, br, Wcl, bcl, Wcr, bcr, sWe, sbe);
    else
        bucket_scatter_body(blockIdx.x - 1, src, dst, gcur, ebuf);
}

// ---------- per-layer transforms body, f16 chunks; 2 columns/thread, 16-row tiles ----------
// node chunk k (16B): [h0 c4k..4k+3 | h1 c4k..4k+3], element idx = (c>>2)*8 + head*4 + (c&3)
template <int BN>
__device__ __forceinline__ void layer_gemm_body(int bid, int nb,
                                                const float* __restrict__ hin,
                                                const float* __restrict__ Wl, const float* __restrict__ bl,
                                                const float* __restrict__ Wr, const float* __restrict__ br,
                                                const float* __restrict__ bns, const float* __restrict__ gamma,
                                                const float* __restrict__ beta,
                                                unsigned short* __restrict__ xl, unsigned short* __restrict__ xr,
                                                float* ssc, float* ssh, h2 (*sh)[36]) {
    int t = threadIdx.x;
    if (BN) {
        if (t < 64) {
            float s = 0.f, sq = 0.f;
#pragma unroll
            for (int r = 0; r < 8; ++r) { s += bns[r * 128 + t]; sq += bns[r * 128 + 64 + t]; }
            float mu = s * (1.f / N_NODES);
            float var = sq * (1.f / N_NODES) - mu * mu;
            float sc = gamma[t] * rsqrtf(var + BN_EPS);
            ssc[t] = sc; ssh[t] = beta[t] - mu * sc;
        }
        __syncthreads();
    }
    int p = t & 127, rh = t >> 7;          // column pair, row half
    int col0 = 2 * p;                       // even: col0,col0+1 same side
    bool isR = col0 >= 128;
    int cw0 = col0 & 127, cw1 = cw0 + 1;
    const float* W = isR ? Wr : Wl;
    h2 w2a[32], w2b[32];
#pragma unroll
    for (int k2 = 0; k2 < 32; ++k2) {
        w2a[k2] = (h2){(_Float16)W[(2 * k2) * 128 + cw0], (_Float16)W[(2 * k2 + 1) * 128 + cw0]};
        w2b[k2] = (h2){(_Float16)W[(2 * k2) * 128 + cw1], (_Float16)W[(2 * k2 + 1) * 128 + cw1]};
    }
    float bja = (isR ? br : bl)[cw0];
    float bjb = (isR ? br : bl)[cw1];
    int head0 = cw0 >> 6, c0 = cw0 & 63;
    int head1 = cw1 >> 6, c1 = cw1 & 63;
    int oidx0 = ((c0 >> 2) << 3) + (head0 << 2) + (c0 & 3);
    int oidx1 = ((c1 >> 2) << 3) + (head1 << 2) + (c1 & 3);
    unsigned short* dstp = isR ? xr : xl;
    for (int base = bid * 16; base < N_NODES; base += nb * 16) {
        __syncthreads();
#pragma unroll
        for (int pass = 0; pass < 2; ++pass) {
            int i = t + pass * 256;
            int node = i >> 5, pr = i & 31;
            int gnode = base + node;
            int cc = pr * 2;
            float2 v = make_float2(0.f, 0.f);
            if (gnode < N_NODES) v = *(const float2*)(hin + (size_t)gnode * 64 + cc);
            if (BN) {
                v.x = fmaxf(v.x * ssc[cc] + ssh[cc], 0.f);
                v.y = fmaxf(v.y * ssc[cc + 1] + ssh[cc + 1], 0.f);
            }
            sh[node][pr] = (h2){(_Float16)v.x, (_Float16)v.y};
        }
        __syncthreads();
        int lim = min(16, N_NODES - base);
        int rend = min(rh * 8 + 8, lim);
        for (int r = rh * 8; r < rend; ++r) {
            float acca = bja, accb = bjb;
            const uint4* r4 = (const uint4*)(&sh[r][0]);
#pragma unroll
            for (int k4 = 0; k4 < 8; ++k4) {
                uint4 u = r4[k4];
                acca = fdot2f(bch2(u.x), w2a[4 * k4 + 0], acca);
                accb = fdot2f(bch2(u.x), w2b[4 * k4 + 0], accb);
                acca = fdot2f(bch2(u.y), w2a[4 * k4 + 1], acca);
                accb = fdot2f(bch2(u.y), w2b[4 * k4 + 1], accb);
                acca = fdot2f(bch2(u.z), w2a[4 * k4 + 2], acca);
                accb = fdot2f(bch2(u.z), w2b[4 * k4 + 2], accb);
                acca = fdot2f(bch2(u.w), w2a[4 * k4 + 3], acca);
                accb = fdot2f(bch2(u.w), w2b[4 * k4 + 3], accb);
            }
            size_t rowb = (size_t)(base + r) * 128;
            dstp[rowb + oidx0] = __builtin_bit_cast(unsigned short, (_Float16)acca);
            dstp[rowb + oidx1] = __builtin_bit_cast(unsigned short, (_Float16)accb);
        }
    }
}

// ---------- combined: blocks 0..255 = bucket_deg (u16-packed LDS histo), 256.. = layer_gemm<0> ----------
__global__ __launch_bounds__(256) void deg_gemm0(const int* __restrict__ gcur,
                                                 const unsigned* __restrict__ ebuf,
                                                 int* __restrict__ deg,
                                                 const float* __restrict__ hin,
                                                 const float* __restrict__ Wl, const float* __restrict__ bl,
                                                 const float* __restrict__ Wr, const float* __restrict__ br,
                                                 unsigned short* __restrict__ xl, unsigned short* __restrict__ xr) {
    __shared__ unsigned ldeg2[NODES_PER_B / 2];   // 25 KB: two u16 counts per u32
    __shared__ float ssc[64], ssh[64];
    __shared__ h2 sh[16][36];
    if (blockIdx.x < NREP * NB) {
        int b = blockIdx.x & (NB - 1), rep = blockIdx.x >> 3;
        for (int j = threadIdx.x; j < NODES_PER_B / 2; j += 256) ldeg2[j] = 0;
        __syncthreads();
        int cnt = gcur[rep * NB + b];
        int base = b * NODES_PER_B;
        const unsigned* p = ebuf + (size_t)(rep * NB + b) * SUBREG;
        for (int i = threadIdx.x; i < cnt; i += 256) {
            unsigned dl = p[i] >> 17;
            atomicAdd(&ldeg2[dl >> 1], 1u << ((dl & 1) * 16));
        }
        __syncthreads();
        for (int j = threadIdx.x; j < NODES_PER_B; j += 256) {
            unsigned v = (ldeg2[j >> 1] >> ((j & 1) * 16)) & 0xffffu;
            if (v) atomicAdd(&deg[base + j], (int)v);
        }
    } else {
        layer_gemm_body<0>(blockIdx.x - NREP * NB, 1024, hin, Wl, bl, Wr, br,
                           nullptr, nullptr, nullptr, xl, xr, ssc, ssh, sh);
    }
}

// ---------- bucket_fine (standalone: col scatter needs quiet L2) ----------
__global__ __launch_bounds__(256) void bucket_fine(const int* __restrict__ gcur,
                                                   const unsigned* __restrict__ ebuf,
                                                   int* __restrict__ cursor, int* __restrict__ col) {
    int b = blockIdx.x & (NB - 1), rep = blockIdx.x >> 3;
    int cnt = gcur[rep * NB + b];
    int base = b * NODES_PER_B;
    const unsigned* p = ebuf + (size_t)(rep * NB + b) * SUBREG;
    for (int i = threadIdx.x; i < cnt; i += 256) {
        unsigned e = p[i];
        int d = base + (int)(e >> 17), s = (int)(e & 0x1FFFFu);
        int pos = atomicAdd(&cursor[d], 1);
        col[pos] = s;
    }
}

// ---------- scans for row_ptr (wave-scan) ----------
__global__ void scan_a(const int* __restrict__ deg, int* __restrict__ row_ptr, int* __restrict__ bsum) {
    __shared__ int wsum[16];
    int tid = threadIdx.x;
    int lane = tid & 63;
    int i = blockIdx.x * 1024 + tid;
    int x = (i < N_NODES) ? deg[i] : 0;
#pragma unroll
    for (int o = 1; o < 64; o <<= 1) {
        int y = __shfl_up(x, o, 64);
        if (lane >= o) x += y;
    }
    if (lane == 63) wsum[tid >> 6] = x;
    __syncthreads();
    if (tid < 16) {
        int s = wsum[tid];
#pragma unroll
        for (int o = 1; o < 16; o <<= 1) {
            int y = __shfl_up(s, o, 16);
            if (tid >= o) s += y;
        }
        wsum[tid] = s;
    }
    __syncthreads();
    int pre = (tid >= 64) ? wsum[(tid >> 6) - 1] : 0;
    int incl = x + pre;
    if (i < N_NODES) row_ptr[i + 1] = incl;
    if (tid == 1023) bsum[blockIdx.x] = incl;
}

// scan_c with inline block-sum prefix
__global__ void scan_c(int* __restrict__ cursor, int* __restrict__ row_ptr, const int* __restrict__ bsum) {
    __shared__ int sp[128];
    int t = threadIdx.x;
    if (t < 128) sp[t] = (t < 98) ? bsum[t] : 0;
    __syncthreads();
    for (int o = 1; o < 128; o <<= 1) {
        int v = (t < 128 && t >= o) ? sp[t - o] : 0;
        __syncthreads();
        if (t < 128) sp[t] += v;
        __syncthreads();
    }
    int i = blockIdx.x * 256 + t;
    if (i < N_NODES) {
        int d = cursor[i];
        int blk = i >> 10;
        int pre = blk ? sp[blk - 1] : 0;
        int incl = row_ptr[i + 1] + pre;
        row_ptr[i + 1] = incl;
        cursor[i] = incl - d;           // exclusive start
        if (i == 0) row_ptr[0] = 0;
    }
}

// ---------- standalone layer 1 transform (BN fused) ----------
__global__ __launch_bounds__(256) void layer_gemm1(const float* __restrict__ hin,
                                                   const float* __restrict__ Wl, const float* __restrict__ bl,
                                                   const float* __restrict__ Wr, const float* __restrict__ br,
                                                   const float* __restrict__ bns, const float* __restrict__ gamma,
                                                   const float* __restrict__ beta,
                                                   unsigned short* __restrict__ xl, unsigned short* __restrict__ xr) {
    __shared__ float ssc[64], ssh[64];
    __shared__ h2 sh[16][36];
    layer_gemm_body<1>(blockIdx.x, gridDim.x, hin, Wl, bl, Wr, br, bns, gamma, beta, xl, xr, ssc, ssh, sh);
}

// ---------- fused GATv2 edge phase: packed-f16 math, depth-3 gated prefetch (R8 verified) ----------
__global__ __launch_bounds__(256) void aggregate(const char* __restrict__ xlb,
                                                 const uint4* __restrict__ xr4,
                                                 const int* __restrict__ row_ptr, const int* __restrict__ col,
                                                 const float* __restrict__ att_l, const float* __restrict__ bias_l,
                                                 float* __restrict__ hn, float* __restrict__ bnsum) {
    int lane = threadIdx.x & 63, wid = threadIdx.x >> 6;
    int q = lane >> 4, k = lane & 15;
    int koff = k << 4;
    h2 atA0 = {(_Float16)att_l[4 * k], (_Float16)att_l[4 * k + 1]};
    h2 atA1 = {(_Float16)att_l[4 * k + 2], (_Float16)att_l[4 * k + 3]};
    h2 atB0 = {(_Float16)att_l[64 + 4 * k], (_Float16)att_l[64 + 4 * k + 1]};
    h2 atB1 = {(_Float16)att_l[64 + 4 * k + 2], (_Float16)att_l[64 + 4 * k + 3]};
    float bi0 = bias_l[4 * k], bi1 = bias_l[4 * k + 1], bi2 = bias_l[4 * k + 2], bi3 = bias_l[4 * k + 3];
    const h2 c06 = {(_Float16)0.6f, (_Float16)0.6f};
    const h2 c04 = {(_Float16)0.4f, (_Float16)0.4f};
    float ps[4] = {0, 0, 0, 0}, pq[4] = {0, 0, 0, 0};
    int w = blockIdx.x * 4 + wid, nw = gridDim.x * 4;
    for (int v = w; v < N_NODES; v += nw) {
        uint4 rp = xr4[(size_t)v * 16 + k];
        h2 rA0 = bch2(rp.x), rA1 = bch2(rp.y), rB0 = bch2(rp.z), rB1 = bch2(rp.w);
        int beg = row_ptr[v], end = row_ptr[v + 1];
        float s0 = 0.f, s1 = 0.f;
        h2 aA0 = {0, 0}, aA1 = {0, 0}, aB0 = {0, 0}, aB1 = {0, 0};
        const int* cptr = col + beg + q;      // padded: safe to over-read 32 entries
        int cv0 = cptr[0], cv1 = cptr[4], cv2 = cptr[8], cv3 = cptr[12];
        cptr += 16;
        uint4 lp0 = *(const uint4*)(xlb + (((size_t)(unsigned)cv0) << 8) + koff);
        uint4 lp1 = lp0, lp2 = lp0;
        if (beg + 4 < end) lp1 = *(const uint4*)(xlb + (((size_t)(unsigned)cv1) << 8) + koff);
        if (beg + 8 < end) lp2 = *(const uint4*)(xlb + (((size_t)(unsigned)cv2) << 8) + koff);
#pragma unroll 2
        for (int i = beg; i < end; i += 4) {
            uint4 lp3 = lp2;
            if (i + 12 < end) lp3 = *(const uint4*)(xlb + (((size_t)(unsigned)cv3) << 8) + koff);
            cv3 = *cptr; cptr += 4;
            h2 lA0 = bch2(lp0.x), lA1 = bch2(lp0.y), lB0 = bch2(lp0.z), lB1 = bch2(lp0.w);
            h2 zA0 = lA0 + rA0, zA1 = lA1 + rA1, zB0 = lB0 + rB0, zB1 = lB1 + rB1;
            h2 yA0 = zA0 * c06 + habs2(zA0) * c04;
            h2 yA1 = zA1 * c06 + habs2(zA1) * c04;
            h2 yB0 = zB0 * c06 + habs2(zB0) * c04;
            h2 yB1 = zB1 * c06 + habs2(zB1) * c04;
            float t0 = fdot2f(yA1, atA1, fdot2f(yA0, atA0, 0.f));
            float t1 = fdot2f(yB1, atB1, fdot2f(yB0, atB0, 0.f));
            t0 = rowsum16(t0); t1 = rowsum16(t1);
            bool valid = (i + q) < end;
            float p0 = valid ? __expf(t0) : 0.f;
            float p1 = valid ? __expf(t1) : 0.f;
            s0 += p0; s1 += p1;
            h2 p0h = {(_Float16)p0, (_Float16)p0};
            h2 p1h = {(_Float16)p1, (_Float16)p1};
            aA0 += p0h * lA0; aA1 += p0h * lA1;
            aB0 += p1h * lB0; aB1 += p1h * lB1;
            lp0 = lp1; lp1 = lp2; lp2 = lp3;
        }
#pragma unroll
        for (int o = 16; o <= 32; o <<= 1) {
            s0 += __shfl_xor(s0, o, 64); s1 += __shfl_xor(s1, o, 64);
            aA0 += shflx_h2(aA0, o); aA1 += shflx_h2(aA1, o);
            aB0 += shflx_h2(aB0, o); aB1 += shflx_h2(aB1, o);
        }
        if (q == 0) {
            float i0 = 0.5f / s0, i1 = 0.5f / s1;
            float hv0 = (float)aA0[0] * i0 + (float)aB0[0] * i1 + bi0;
            float hv1 = (float)aA0[1] * i0 + (float)aB0[1] * i1 + bi1;
            float hv2 = (float)aA1[0] * i0 + (float)aB1[0] * i1 + bi2;
            float hv3 = (float)aA1[1] * i0 + (float)aB1[1] * i1 + bi3;
            *(float4*)(hn + (size_t)v * 64 + 4 * k) = make_float4(hv0, hv1, hv2, hv3);
            ps[0] += hv0; pq[0] += hv0 * hv0;
            ps[1] += hv1; pq[1] += hv1 * hv1;
            ps[2] += hv2; pq[2] += hv2 * hv2;
            ps[3] += hv3; pq[3] += hv3 * hv3;
        }
    }
    __shared__ float sb[2][4][64];
    if (q == 0) {
#pragma unroll
        for (int j = 0; j < 4; ++j) { sb[0][wid][4 * k + j] = ps[j]; sb[1][wid][4 * k + j] = pq[j]; }
    }
    __syncthreads();
    float* dstb = bnsum + (size_t)(blockIdx.x & 7) * 128;
    int t = threadIdx.x;
    if (t < 64)
        atomicAdd(&dstb[t], sb[0][0][t] + sb[0][1][t] + sb[0][2][t] + sb[0][3][t]);
    else if (t < 128)
        atomicAdd(&dstb[t], sb[1][0][t - 64] + sb[1][1][t - 64] + sb[1][2][t - 64] + sb[1][3][t - 64]);
}

// ---------- pool: batch sorted -> per-graph blocks via binary search; BN fused ----------
__global__ __launch_bounds__(256) void pool2(const float* __restrict__ hn, const int* __restrict__ batch,
                                             const float* __restrict__ bns, const float* __restrict__ gamma,
                                             const float* __restrict__ beta,
                                             float* __restrict__ gpool, float* __restrict__ gcnt) {
    __shared__ float ssc[64], ssh[64];
    int t = threadIdx.x;
    if (t < 64) {
        float s = 0.f, sq = 0.f;
#pragma unroll
        for (int r = 0; r < 8; ++r) { s += bns[r * 128 + t]; sq += bns[r * 128 + 64 + t]; }
        float mu = s * (1.f / N_NODES);
        float var = sq * (1.f / N_NODES) - mu * mu;
        float sc = gamma[t] * rsqrtf(var + BN_EPS);
        ssc[t] = sc; ssh[t] = beta[t] - mu * sc;
    }
    __syncthreads();
    int g = blockIdx.x >> 2, part = blockIdx.x & 3;
    int lo = 0, hi = N_NODES;
    while (lo < hi) { int mid = (lo + hi) >> 1; if (batch[mid] < g) lo = mid + 1; else hi = mid; }
    int lo2 = lo, hi2 = N_NODES;
    while (lo2 < hi2) { int mid = (lo2 + hi2) >> 1; if (batch[mid] < g + 1) lo2 = mid + 1; else hi2 = mid; }
    int len = lo2 - lo;
    if (part == 0 && t == 0) gcnt[g] = (float)len;
    int n0 = lo + (len * part) / 4, n1 = lo + (len * (part + 1)) / 4;
    int c = t & 63, r = t >> 6;
    float sc = ssc[c], sh = ssh[c];
    float acc = 0.f;
    for (int node = n0 + r; node < n1; node += 4)
        acc += fmaxf(hn[(size_t)node * 64 + c] * sc + sh, 0.f);
    __shared__ float sb[4][64];
    sb[r][c] = acc;
    __syncthreads();
    if (r == 0)
        atomicAdd(&gpool[g * 64 + c], sb[0][c] + sb[1][c] + sb[2][c] + sb[3][c]);
}

// ---------- classifier ----------
__global__ void classify(const float* __restrict__ gpool, const float* __restrict__ gcnt,
                         const float* __restrict__ Wc, const float* __restrict__ bc, float* __restrict__ out) {
    int t = threadIdx.x;
    if (t >= 640) return;
    int b = t / 10, o = t % 10;
    float inv = 1.f / fmaxf(gcnt[b], 1.f);
    float acc = 0.f;
    for (int c = 0; c < 64; ++c) acc += gpool[b * 64 + c] * Wc[c * 10 + o];
    out[t] = acc * inv + bc[o];
}

extern "C" void kernel_launch(void* const* d_in, const int* in_sizes, int n_in,
                              void* d_out, int out_size, void* d_ws, size_t ws_size,
                              hipStream_t stream) {
    (void)in_sizes; (void)n_in; (void)out_size; (void)ws_size;
    const float* x     = (const float*)d_in[0];
    const int*   ei    = (const int*)d_in[1];
    const int*   batch = (const int*)d_in[2];
    const float* W_enc = (const float*)d_in[3];
    const float* b_enc = (const float*)d_in[4];
    const float* Wl    = (const float*)d_in[5];
    const float* bl    = (const float*)d_in[6];
    const float* Wr    = (const float*)d_in[7];
    const float* br    = (const float*)d_in[8];
    const float* att   = (const float*)d_in[9];
    const float* bias  = (const float*)d_in[10];
    const float* gamma = (const float*)d_in[11];
    const float* beta  = (const float*)d_in[12];
    const float* Wc    = (const float*)d_in[13];
    const float* bc    = (const float*)d_in[14];
    float* out = (float*)d_out;

    char* ws = (char*)d_ws;
    size_t off = 0;
    auto A = [&](size_t bytes) { size_t r = off; off += (bytes + 255) & ~(size_t)255; return r; };

    int* row_ptr = (int*)(ws + A((N_NODES + 1) * 4));
    // colv followed immediately by the contiguous zero region (one memset)
    size_t colv_off = A((size_t)EP_EDGES * 4 + 426240);
    int* colv = (int*)(ws + colv_off);
    char* zbase = ws + colv_off + (size_t)EP_EDGES * 4;
    int*   cursor = (int*)(zbase + 128);              // 400000 B  (col pad = zbase+0, 128 B)
    int*   gcur   = (int*)(zbase + 400128);           // 1024 B
    float* bns    = (float*)(zbase + 401152);         // 8192 B (2 layers x 8 reps x 128)
    float* gpool  = (float*)(zbase + 409344);         // 16384 B
    float* gcnt   = (float*)(zbase + 425728);         // 256 B
    const size_t ZBYTES = 426240;

    float* h   = (float*)(ws + A((size_t)N_NODES * 64 * 4));
    float* hn  = (float*)(ws + A((size_t)N_NODES * 64 * 4));
    unsigned short* xl = (unsigned short*)(ws + A((size_t)N_NODES * 128 * 2));
    unsigned short* xr = (unsigned short*)(ws + A((size_t)N_NODES * 128 * 2));
    unsigned* ebuf = (unsigned*)(ws + A((size_t)NREP * NB * SUBREG * 4));
    int* bsum  = (int*)(ws + A(512));
    float* Wcl = (float*)(ws + A(64 * 128 * 4));
    float* Wcr = (float*)(ws + A(64 * 128 * 4));
    float* bcl = (float*)(ws + A(128 * 4));
    float* bcr = (float*)(ws + A(128 * 4));

    const int* srcv = ei;
    const int* dstv = ei + E_EDGES;

    hipMemsetAsync(zbase, 0, ZBYTES, stream);

    // bucket_scatter ∥ fuse_enc
    scatter_fuse<<<SCATTER_BLKS + 1, 256, 0, stream>>>(srcv, dstv, gcur, ebuf,
                                                       W_enc, b_enc, Wl, bl, Wr, br,
                                                       Wcl, bcl, Wcr, bcr);
    // bucket_deg ∥ layer_gemm<0> (deg is LDS-only: no L2 thrash against gemm writes)
    deg_gemm0<<<NREP * NB + 1024, 256, 0, stream>>>(gcur, ebuf, cursor,
                                                    x, Wcl, bcl, Wcr, bcr, xl, xr);
    scan_a<<<98, 1024, 0, stream>>>(cursor, row_ptr, bsum);
    scan_c<<<(N_NODES + 255) / 256, 256, 0, stream>>>(cursor, row_ptr, bsum);
    bucket_fine<<<NREP * NB, 256, 0, stream>>>(gcur, ebuf, cursor, colv);

    aggregate<<<4096, 256, 0, stream>>>((const char*)xl, (const uint4*)xr,
                                        row_ptr, colv, att, bias, hn, bns);
    // layer 1 (BN of layer 0 folded into prologue)
    layer_gemm1<<<1024, 256, 0, stream>>>(hn, Wl + 64 * 128, bl + 128, Wr + 64 * 128, br + 128,
                                          bns, gamma, beta, xl, xr);
    aggregate<<<4096, 256, 0, stream>>>((const char*)xl, (const uint4*)xr,
                                        row_ptr, colv, att + 128, bias + 64, h, bns + 1024);

    // pool (BN of layer 1 fused) + classifier
    pool2<<<256, 256, 0, stream>>>(h, batch, bns + 1024, gamma + 64, beta + 64, gpool, gcnt);
    classify<<<1, 640, 0, stream>>>(gpool, gcnt, Wc, bc, out);
}